// Round 4
// baseline (116.563 us; speedup 1.0000x reference)
//
#include <hip/hip_runtime.h>
#include <hip/hip_bf16.h>
#include <stdint.h>

// Problem constants: B=32, T=512, C=F=384, M=2048.
#define B_ 32
#define T_ 512
#define C_ 384
#define F_ 384
#define M_ 2048
#define PT (T_ + 2)      // padded time rows per batch (halo for K=3 conv)
#define KTOT (3 * C_)    // GEMM K = 1152

typedef __bf16 bf16x8 __attribute__((ext_vector_type(8)));
typedef float  f32x4  __attribute__((ext_vector_type(4)));
typedef unsigned short ushort_t;

__device__ __forceinline__ float bf2f(uint32_t bits16) {
  union { uint32_t u; float f; } c; c.u = bits16 << 16; return c.f;
}
__device__ __forceinline__ ushort_t f2bf(float f) {
  __hip_bfloat16 h = __float2bfloat16(f);
  return *reinterpret_cast<ushort_t*>(&h);
}
__device__ __forceinline__ void gload16(const void* g, void* l) {
  __builtin_amdgcn_global_load_lds(
      (const __attribute__((address_space(1))) uint32_t*)g,
      (__attribute__((address_space(3))) uint32_t*)l, 16, 0, 0);
}

// ---------------------------------------------------------------------------
// Fused prep: 3 grid regions (x convert+mask+pad | weight transposes | cumsum).
#define NXB 6168   // = B*PT*(C/4)/256
#define NWB 3456   // = 2*F*KTOT/256
__global__ __launch_bounds__(256) void prep_kernel(
    const float* __restrict__ x, const float* __restrict__ mask,
    const int* __restrict__ target,
    const float* __restrict__ w1, const float* __restrict__ w2,
    ushort_t* __restrict__ xm, ushort_t* __restrict__ x1p,
    ushort_t* __restrict__ wt1, ushort_t* __restrict__ wt2,
    int* __restrict__ cs) {
  const int gid = blockIdx.x;
  const int tid = threadIdx.x;
  if (gid < NXB) {
    int i = gid * 256 + tid;            // one thread per 4 channels
    int r = i / (C_ / 4);
    int c4 = (i % (C_ / 4)) * 4;
    int b = r / PT, pr = r % PT;
    uint32_t p0 = 0, p1 = 0;
    if (pr >= 1 && pr <= T_) {
      int t = pr - 1;
      const float4 v = *(const float4*)(x + ((size_t)b * T_ + t) * C_ + c4);
      float m = mask[b * T_ + t];
      p0 = (uint32_t)f2bf(v.x * m) | ((uint32_t)f2bf(v.y * m) << 16);
      p1 = (uint32_t)f2bf(v.z * m) | ((uint32_t)f2bf(v.w * m) << 16);
    } else {
      // halo row: x1p needs zeros too (gemm1 only writes rows 1..T)
      *(uint2*)(x1p + (size_t)r * C_ + c4) = make_uint2(0, 0);
    }
    *(uint2*)(xm + (size_t)r * C_ + c4) = make_uint2(p0, p1);
  } else if (gid < NXB + NWB) {
    int idx = (gid - NXB) * 256 + tid;  // 0 .. 2*F*KTOT
    int w = idx >= F_ * KTOT;
    int o = idx - (w ? F_ * KTOT : 0);
    int n = o / KTOT, rem = o % KTOT, kk = rem / C_, c = rem % C_;
    const float* src = w ? w2 : w1;
    ushort_t* dst = w ? wt2 : wt1;
    dst[o] = f2bf(src[(n * C_ + c) * 3 + kk]);
  } else {
    int b = (gid - NXB - NWB) * 4 + (tid >> 6);
    int lane = tid & 63;
    int base = b * T_ + lane * 8;
    int v[8];
#pragma unroll
    for (int i = 0; i < 8; ++i) v[i] = target[base + i];
#pragma unroll
    for (int i = 1; i < 8; ++i) v[i] += v[i - 1];
    int tot = v[7];
    int inc = tot;
#pragma unroll
    for (int d = 1; d < 64; d <<= 1) {
      int t = __shfl_up(inc, d);
      if (lane >= d) inc += t;
    }
    int excl = inc - tot;
#pragma unroll
    for (int i = 0; i < 8; ++i) cs[base + i] = v[i] + excl;
  }
}

// ---------------------------------------------------------------------------
// Fused conv-GEMM + bias + ReLU + LayerNorm (+ final linear for LAST).
// Full-N block: BN=384 (all of F), BM=64 rows. 256 threads (4 waves), wave w
// owns n in [w*96, w*96+96) x all 64 m. Grid = 256 = 1 block/CU.
// Double-buffered LDS, 2-phase pipeline: issue next tile's global_load_lds
// BEFORE computing current tile; ONE barrier per K-step (T3-min recipe).
// D[n][m]: A = W rows (n), B = X rows (m); both frags contiguous in k.
constexpr int BUFB = (F_ + 64) * 128;  // 56 KB per buffer (W 48K | X 8K)

template <bool LAST>
__global__ __launch_bounds__(256, 1) void gemm_ln_kernel(
    const ushort_t* __restrict__ xp,   // [B][PT][C] bf16, zero halos
    const ushort_t* __restrict__ wt,   // [F][KTOT] bf16
    const float* __restrict__ bias,    // [F]
    const float* __restrict__ g,       // [F]
    const float* __restrict__ be,      // [F]
    const float* __restrict__ wl,      // [F]   (LAST)
    const float* __restrict__ bl,      // [1]   (LAST)
    const float* __restrict__ mask,    // [B*T] (LAST)
    ushort_t* __restrict__ xout,       // [B][PT][C] (LAST=false)
    float* __restrict__ dpo) {         // [B*T]      (LAST=true)
  __shared__ char lds[2 * BUFB];       // 112 KB double buffer
  __shared__ float red[4][64][2];
  __shared__ float stats[64][2];

  const int tid = threadIdx.x;
  const int l = tid & 63, q = l >> 4, r16 = l & 15;
  const int wid = tid >> 6;            // 0..3
  const int b = blockIdx.x >> 3, t0 = (blockIdx.x & 7) * 64;
  const ushort_t* xb = xp + (size_t)b * PT * C_;

  f32x4 acc[6][4];
#pragma unroll
  for (int fn = 0; fn < 6; ++fn)
#pragma unroll
    for (int fm = 0; fm < 4; ++fm) acc[fn][fm] = (f32x4){0.f, 0.f, 0.f, 0.f};

  // Stage K-step s into buffer `buf`: W [384][64] (12 x 4KB) + X [64][64]
  // (2 x 4KB). 16B/lane, linear LDS dest, chunk-XOR swizzle via pre-swizzled
  // global source (both-sides-or-neither, rule 21).
  auto STAGE = [&](int buf, int s) {
    const int kk = s / 6, c0 = (s % 6) * 64;
    char* ldsW = lds + buf * BUFB;
    char* ldsX = ldsW + F_ * 128;
#pragma unroll
    for (int i = 0; i < 12; ++i) {
      int lin = i * 4096 + tid * 16;
      int row = lin >> 7, ch = ((lin >> 4) & 7) ^ (row & 7);
      gload16(wt + (size_t)row * KTOT + kk * C_ + c0 + ch * 8,
              ldsW + i * 4096 + (wid << 10));
    }
#pragma unroll
    for (int i = 0; i < 2; ++i) {
      int lin = i * 4096 + tid * 16;
      int row = lin >> 7, ch = ((lin >> 4) & 7) ^ (row & 7);
      gload16(xb + (size_t)(t0 + row + kk) * C_ + c0 + ch * 8,
              ldsX + i * 4096 + (wid << 10));
    }
  };

  STAGE(0, 0);
  __syncthreads();  // drains vmcnt(0): buffer 0 ready

  int cur = 0;
  for (int s = 0; s < 18; ++s) {
    if (s < 17) STAGE(cur ^ 1, s + 1);  // prefetch next tile (flies under MFMA)
    const char* ldsW = lds + cur * BUFB;
    const char* ldsX = ldsW + F_ * 128;
#pragma unroll
    for (int ks = 0; ks < 2; ++ks) {
      bf16x8 af[6], bx[4];
#pragma unroll
      for (int fn = 0; fn < 6; ++fn) {
        int rr = wid * 96 + fn * 16 + r16;
        int ch = (ks * 4 + q) ^ (rr & 7);
        af[fn] = *(const bf16x8*)(ldsW + rr * 128 + ch * 16);
      }
#pragma unroll
      for (int fm = 0; fm < 4; ++fm) {
        int rr = fm * 16 + r16;
        int ch = (ks * 4 + q) ^ (rr & 7);
        bx[fm] = *(const bf16x8*)(ldsX + rr * 128 + ch * 16);
      }
#pragma unroll
      for (int fn = 0; fn < 6; ++fn)
#pragma unroll
        for (int fm = 0; fm < 4; ++fm)
          acc[fn][fm] = __builtin_amdgcn_mfma_f32_16x16x32_bf16(
              af[fn], bx[fm], acc[fn][fm], 0, 0, 0);
    }
    __syncthreads();  // one drain per step: next stage done, reads done
    cur ^= 1;
  }

  // --- epilogue: bias + ReLU (in place) ---
#pragma unroll
  for (int fn = 0; fn < 6; ++fn) {
    const int nb = wid * 96 + fn * 16 + q * 4;
    float b0 = bias[nb], b1 = bias[nb + 1], b2 = bias[nb + 2], b3 = bias[nb + 3];
#pragma unroll
    for (int fm = 0; fm < 4; ++fm) {
      acc[fn][fm][0] = fmaxf(acc[fn][fm][0] + b0, 0.f);
      acc[fn][fm][1] = fmaxf(acc[fn][fm][1] + b1, 0.f);
      acc[fn][fm][2] = fmaxf(acc[fn][fm][2] + b2, 0.f);
      acc[fn][fm][3] = fmaxf(acc[fn][fm][3] + b3, 0.f);
    }
  }

  // --- LN stats: per-m sum/sumsq over the wave's 96 n, then cross-wave ---
#pragma unroll
  for (int fm = 0; fm < 4; ++fm) {
    float s = 0.f, s2 = 0.f;
#pragma unroll
    for (int fn = 0; fn < 6; ++fn)
#pragma unroll
      for (int j = 0; j < 4; ++j) {
        float v = acc[fn][fm][j];
        s += v; s2 += v * v;
      }
    s += __shfl_xor(s, 16); s += __shfl_xor(s, 32);
    s2 += __shfl_xor(s2, 16); s2 += __shfl_xor(s2, 32);
    if (l < 16) { red[wid][fm * 16 + r16][0] = s; red[wid][fm * 16 + r16][1] = s2; }
  }
  __syncthreads();
  if (tid < 64) {
    float S = 0.f, S2 = 0.f;
#pragma unroll
    for (int w = 0; w < 4; ++w) { S += red[w][tid][0]; S2 += red[w][tid][1]; }
    float mu = S / F_;
    stats[tid][0] = mu;
    stats[tid][1] = rsqrtf(S2 / F_ - mu * mu + 1e-5f);
  }
  __syncthreads();

  if (!LAST) {
#pragma unroll
    for (int fn = 0; fn < 6; ++fn) {
      const int nb = wid * 96 + fn * 16 + q * 4;
      float g0 = g[nb], g1 = g[nb + 1], g2 = g[nb + 2], g3 = g[nb + 3];
      float e0 = be[nb], e1 = be[nb + 1], e2 = be[nb + 2], e3 = be[nb + 3];
#pragma unroll
      for (int fm = 0; fm < 4; ++fm) {
        const int m = fm * 16 + r16;
        const float mu = stats[m][0], rs = stats[m][1];
        float a0 = (acc[fn][fm][0] - mu) * rs * g0 + e0;
        float a1 = (acc[fn][fm][1] - mu) * rs * g1 + e1;
        float a2 = (acc[fn][fm][2] - mu) * rs * g2 + e2;
        float a3 = (acc[fn][fm][3] - mu) * rs * g3 + e3;
        uint32_t p0 = (uint32_t)f2bf(a0) | ((uint32_t)f2bf(a1) << 16);
        uint32_t p1 = (uint32_t)f2bf(a2) | ((uint32_t)f2bf(a3) << 16);
        *(uint2*)(xout + ((size_t)(b * PT + 1 + t0 + m)) * C_ + nb) =
            make_uint2(p0, p1);
      }
    }
  } else {
    float p[4] = {0.f, 0.f, 0.f, 0.f};
#pragma unroll
    for (int fn = 0; fn < 6; ++fn) {
      const int nb = wid * 96 + fn * 16 + q * 4;
      float g0 = g[nb], g1 = g[nb + 1], g2 = g[nb + 2], g3 = g[nb + 3];
      float e0 = be[nb], e1 = be[nb + 1], e2 = be[nb + 2], e3 = be[nb + 3];
      float l0 = wl[nb], l1 = wl[nb + 1], l2 = wl[nb + 2], l3 = wl[nb + 3];
#pragma unroll
      for (int fm = 0; fm < 4; ++fm) {
        const int m = fm * 16 + r16;
        const float mu = stats[m][0], rs = stats[m][1];
        p[fm] += ((acc[fn][fm][0] - mu) * rs * g0 + e0) * l0 +
                 ((acc[fn][fm][1] - mu) * rs * g1 + e1) * l1 +
                 ((acc[fn][fm][2] - mu) * rs * g2 + e2) * l2 +
                 ((acc[fn][fm][3] - mu) * rs * g3 + e3) * l3;
      }
    }
    __syncthreads();  // red reuse
#pragma unroll
    for (int fm = 0; fm < 4; ++fm) {
      float s = p[fm];
      s += __shfl_xor(s, 16); s += __shfl_xor(s, 32);
      if (l < 16) red[wid][fm * 16 + r16][0] = s;
    }
    __syncthreads();
    if (tid < 64) {
      float S = 0.f;
#pragma unroll
      for (int w = 0; w < 4; ++w) S += red[w][tid][0];
      int t = t0 + tid;
      dpo[b * T_ + t] = (S + bl[0]) * mask[b * T_ + t];
    }
  }
}

// ---------------------------------------------------------------------------
__global__ __launch_bounds__(256) void expand_kernel(
    const float* __restrict__ enc,  // [B,T,C] f32
    const int* __restrict__ cs,     // [B,T]
    float* __restrict__ out,        // [B,M,C]
    float* __restrict__ dec) {      // [B,M] (as float)
  __shared__ int scs[T_];
  const int blk = blockIdx.x;  // B * (M/4) blocks
  const int b = blk / (M_ / 4);
  const int p0 = (blk - b * (M_ / 4)) * 4;
  for (int i = threadIdx.x; i < T_; i += 256) scs[i] = cs[b * T_ + i];
  __syncthreads();

  const int lane = threadIdx.x & 63;
  const int wid = threadIdx.x >> 6;
  const int pos = p0 + wid;
  const int total = scs[T_ - 1];
  const bool valid = pos < total;

  int idx = 0;
#pragma unroll
  for (int step = 512; step; step >>= 1)
    if (idx + step <= T_ && scs[idx + step - 1] <= pos) idx += step;
  int src = idx < T_ ? idx : T_ - 1;

  const float4* srow = (const float4*)(enc + ((size_t)b * T_ + src) * C_);
  float4* orow = (float4*)(out + ((size_t)b * M_ + pos) * C_);
  const float4 zero = make_float4(0.f, 0.f, 0.f, 0.f);
#pragma unroll
  for (int j = 0; j < 2; ++j) {
    int c4 = j * 64 + lane;
    if (c4 < C_ / 4) orow[c4] = valid ? srow[c4] : zero;
  }
  if (lane == 0) dec[b * M_ + pos] = valid ? (float)(pos + 1) : 0.f;
}

// ---------------------------------------------------------------------------
extern "C" void kernel_launch(void* const* d_in, const int* in_sizes, int n_in,
                              void* d_out, int out_size, void* d_ws,
                              size_t ws_size, hipStream_t stream) {
  const float* enc    = (const float*)d_in[0];
  const float* mask   = (const float*)d_in[1];
  const int*   target = (const int*)d_in[2];
  const float* w1    = (const float*)d_in[4];
  const float* b1    = (const float*)d_in[5];
  const float* g1    = (const float*)d_in[6];
  const float* beta1 = (const float*)d_in[7];
  const float* w2    = (const float*)d_in[8];
  const float* b2    = (const float*)d_in[9];
  const float* g2    = (const float*)d_in[10];
  const float* beta2 = (const float*)d_in[11];
  const float* wl    = (const float*)d_in[12];
  const float* bl    = (const float*)d_in[13];

  // Workspace (bf16): xm | x1p (both padded) | wt1 | wt2 | cs (i32)
  ushort_t* xm  = (ushort_t*)d_ws;                    // [B][PT][C]
  ushort_t* x1p = xm + (size_t)B_ * PT * C_;          // [B][PT][C]
  ushort_t* wt1 = x1p + (size_t)B_ * PT * C_;         // [F][KTOT]
  ushort_t* wt2 = wt1 + (size_t)F_ * KTOT;
  int*      cs  = (int*)(wt2 + (size_t)F_ * KTOT);    // [B][T]

  float* out0 = (float*)d_out;                        // [B,M,C]
  float* dec  = out0 + (size_t)B_ * M_ * C_;          // [B,M]
  float* dpo  = dec + (size_t)B_ * M_;                // [B,T]

  prep_kernel<<<NXB + NWB + 8, 256, 0, stream>>>(
      enc, mask, target, w1, w2, xm, x1p, wt1, wt2, cs);

  gemm_ln_kernel<false><<<B_ * (T_ / 64), 256, 0, stream>>>(
      xm, wt1, b1, g1, beta1, nullptr, nullptr, nullptr, x1p, nullptr);
  gemm_ln_kernel<true><<<B_ * (T_ / 64), 256, 0, stream>>>(
      x1p, wt2, b2, g2, beta2, wl, bl, mask, nullptr, dpo);

  expand_kernel<<<(B_ * M_) / 4, 256, 0, stream>>>(enc, cs, out0, dec);
}

// Round 5
// 101.011 us; speedup vs baseline: 1.1540x; 1.1540x over previous
//
#include <hip/hip_runtime.h>
#include <hip/hip_bf16.h>
#include <stdint.h>

// Problem constants: B=32, T=512, C=F=384, M=2048.
#define B_ 32
#define T_ 512
#define C_ 384
#define F_ 384
#define M_ 2048
#define PT (T_ + 2)      // padded time rows per batch (halo for K=3 conv)
#define KTOT (3 * C_)    // GEMM K = 1152

typedef __bf16 bf16x8 __attribute__((ext_vector_type(8)));
typedef float  f32x4  __attribute__((ext_vector_type(4)));
typedef unsigned short ushort_t;

__device__ __forceinline__ float bf2f(uint32_t bits16) {
  union { uint32_t u; float f; } c; c.u = bits16 << 16; return c.f;
}
__device__ __forceinline__ ushort_t f2bf(float f) {
  __hip_bfloat16 h = __float2bfloat16(f);
  return *reinterpret_cast<ushort_t*>(&h);
}
__device__ __forceinline__ void gload16(const void* g, void* l) {
  __builtin_amdgcn_global_load_lds(
      (const __attribute__((address_space(1))) uint32_t*)g,
      (__attribute__((address_space(3))) uint32_t*)l, 16, 0, 0);
}

// ---------------------------------------------------------------------------
// Fused prep: 3 grid regions (x convert+mask+pad | weight transposes | cumsum).
#define NXB 6168   // = B*PT*(C/4)/256
#define NWB 3456   // = 2*F*KTOT/256
__global__ __launch_bounds__(256) void prep_kernel(
    const float* __restrict__ x, const float* __restrict__ mask,
    const int* __restrict__ target,
    const float* __restrict__ w1, const float* __restrict__ w2,
    ushort_t* __restrict__ xm, ushort_t* __restrict__ x1p,
    ushort_t* __restrict__ wt1, ushort_t* __restrict__ wt2,
    int* __restrict__ cs) {
  const int gid = blockIdx.x;
  const int tid = threadIdx.x;
  if (gid < NXB) {
    int i = gid * 256 + tid;            // one thread per 4 channels
    int r = i / (C_ / 4);
    int c4 = (i % (C_ / 4)) * 4;
    int b = r / PT, pr = r % PT;
    uint32_t p0 = 0, p1 = 0;
    if (pr >= 1 && pr <= T_) {
      int t = pr - 1;
      const float4 v = *(const float4*)(x + ((size_t)b * T_ + t) * C_ + c4);
      float m = mask[b * T_ + t];
      p0 = (uint32_t)f2bf(v.x * m) | ((uint32_t)f2bf(v.y * m) << 16);
      p1 = (uint32_t)f2bf(v.z * m) | ((uint32_t)f2bf(v.w * m) << 16);
    } else {
      // halo row: x1p needs zeros too (gemm1 only writes rows 1..T)
      *(uint2*)(x1p + (size_t)r * C_ + c4) = make_uint2(0, 0);
    }
    *(uint2*)(xm + (size_t)r * C_ + c4) = make_uint2(p0, p1);
  } else if (gid < NXB + NWB) {
    int idx = (gid - NXB) * 256 + tid;  // 0 .. 2*F*KTOT
    int w = idx >= F_ * KTOT;
    int o = idx - (w ? F_ * KTOT : 0);
    int n = o / KTOT, rem = o % KTOT, kk = rem / C_, c = rem % C_;
    const float* src = w ? w2 : w1;
    ushort_t* dst = w ? wt2 : wt1;
    dst[o] = f2bf(src[(n * C_ + c) * 3 + kk]);
  } else {
    int b = (gid - NXB - NWB) * 4 + (tid >> 6);
    int lane = tid & 63;
    int base = b * T_ + lane * 8;
    int v[8];
#pragma unroll
    for (int i = 0; i < 8; ++i) v[i] = target[base + i];
#pragma unroll
    for (int i = 1; i < 8; ++i) v[i] += v[i - 1];
    int tot = v[7];
    int inc = tot;
#pragma unroll
    for (int d = 1; d < 64; d <<= 1) {
      int t = __shfl_up(inc, d);
      if (lane >= d) inc += t;
    }
    int excl = inc - tot;
#pragma unroll
    for (int i = 0; i < 8; ++i) cs[base + i] = v[i] + excl;
  }
}

// ---------------------------------------------------------------------------
// Fused conv-GEMM + bias + ReLU + LayerNorm (+ final linear for LAST).
// Full-N block: BN=384 (all of F), BM=64 rows, 512 threads (8 waves),
// wave w owns n in [w*48, w*48+48) x all 64 m -> zero cross-wave W duplication.
// Grid = 256 = 1 block/CU (LDS-limited), 2 waves/SIMD (the R4 lesson: never 1).
// Double-buffered LDS, 2-phase pipeline: issue next tile's global_load_lds
// BEFORE computing the current tile; ONE barrier per K-step (T3-min recipe).
// D[n][m]: A = W rows (n), B = X rows (m); both frags contiguous in k.
constexpr int BUFB = (F_ + 64) * 128;  // 56 KB per buffer (W 48K | X 8K)

template <bool LAST>
__global__ __launch_bounds__(512, 1) void gemm_ln_kernel(
    const ushort_t* __restrict__ xp,   // [B][PT][C] bf16, zero halos
    const ushort_t* __restrict__ wt,   // [F][KTOT] bf16
    const float* __restrict__ bias,    // [F]
    const float* __restrict__ g,       // [F]
    const float* __restrict__ be,      // [F]
    const float* __restrict__ wl,      // [F]   (LAST)
    const float* __restrict__ bl,      // [1]   (LAST)
    const float* __restrict__ mask,    // [B*T] (LAST)
    ushort_t* __restrict__ xout,       // [B][PT][C] (LAST=false)
    float* __restrict__ dpo) {         // [B*T]      (LAST=true)
  __shared__ char lds[2 * BUFB];       // 112 KB double buffer
  __shared__ float red[8][64][2];
  __shared__ float stats[64][2];

  const int tid = threadIdx.x;
  const int l = tid & 63, q = l >> 4, r16 = l & 15;
  const int wid = tid >> 6;            // 0..7
  const int b = blockIdx.x >> 3, t0 = (blockIdx.x & 7) * 64;
  const ushort_t* xb = xp + (size_t)b * PT * C_;

  f32x4 acc[3][4];
#pragma unroll
  for (int fn = 0; fn < 3; ++fn)
#pragma unroll
    for (int fm = 0; fm < 4; ++fm) acc[fn][fm] = (f32x4){0.f, 0.f, 0.f, 0.f};

  // Stage K-step s into buffer `buf`: W [384][64] (6 x 8KB) + X [64][64]
  // (1 x 8KB). 16B/lane, linear LDS dest, chunk-XOR swizzle via pre-swizzled
  // global source (both-sides-or-neither, rule 21).
  auto STAGE = [&](int buf, int s) {
    const int kk = s / 6, c0 = (s % 6) * 64;
    char* ldsW = lds + buf * BUFB;
    char* ldsX = ldsW + F_ * 128;
#pragma unroll
    for (int i = 0; i < 6; ++i) {
      int lin = i * 8192 + tid * 16;
      int row = lin >> 7, ch = ((lin >> 4) & 7) ^ (row & 7);
      gload16(wt + (size_t)row * KTOT + kk * C_ + c0 + ch * 8,
              ldsW + i * 8192 + (wid << 10));
    }
    {
      int lin = tid * 16;
      int row = lin >> 7, ch = ((lin >> 4) & 7) ^ (row & 7);
      gload16(xb + (size_t)(t0 + row + kk) * C_ + c0 + ch * 8,
              ldsX + (wid << 10));
    }
  };

  STAGE(0, 0);
  __syncthreads();  // drains vmcnt(0): buffer 0 ready

  int cur = 0;
  for (int s = 0; s < 18; ++s) {
    if (s < 17) STAGE(cur ^ 1, s + 1);  // prefetch flies under this step's work
    const char* ldsW = lds + cur * BUFB;
    const char* ldsX = ldsW + F_ * 128;
#pragma unroll
    for (int ks = 0; ks < 2; ++ks) {
      bf16x8 af[3], bx[4];
#pragma unroll
      for (int fn = 0; fn < 3; ++fn) {
        int rr = wid * 48 + fn * 16 + r16;
        int ch = (ks * 4 + q) ^ (rr & 7);
        af[fn] = *(const bf16x8*)(ldsW + rr * 128 + ch * 16);
      }
#pragma unroll
      for (int fm = 0; fm < 4; ++fm) {
        int rr = fm * 16 + r16;
        int ch = (ks * 4 + q) ^ (rr & 7);
        bx[fm] = *(const bf16x8*)(ldsX + rr * 128 + ch * 16);
      }
#pragma unroll
      for (int fn = 0; fn < 3; ++fn)
#pragma unroll
        for (int fm = 0; fm < 4; ++fm)
          acc[fn][fm] = __builtin_amdgcn_mfma_f32_16x16x32_bf16(
              af[fn], bx[fm], acc[fn][fm], 0, 0, 0);
    }
    __syncthreads();  // one drain per step: stage(s+1) done + reads(s) done
    cur ^= 1;
  }

  // --- epilogue: bias + ReLU (in place) ---
#pragma unroll
  for (int fn = 0; fn < 3; ++fn) {
    const int nb = wid * 48 + fn * 16 + q * 4;
    float b0 = bias[nb], b1 = bias[nb + 1], b2 = bias[nb + 2], b3 = bias[nb + 3];
#pragma unroll
    for (int fm = 0; fm < 4; ++fm) {
      acc[fn][fm][0] = fmaxf(acc[fn][fm][0] + b0, 0.f);
      acc[fn][fm][1] = fmaxf(acc[fn][fm][1] + b1, 0.f);
      acc[fn][fm][2] = fmaxf(acc[fn][fm][2] + b2, 0.f);
      acc[fn][fm][3] = fmaxf(acc[fn][fm][3] + b3, 0.f);
    }
  }

  // --- LN stats: per-m sum/sumsq over the wave's 48 n, then cross-wave ---
#pragma unroll
  for (int fm = 0; fm < 4; ++fm) {
    float s = 0.f, s2 = 0.f;
#pragma unroll
    for (int fn = 0; fn < 3; ++fn)
#pragma unroll
      for (int j = 0; j < 4; ++j) {
        float v = acc[fn][fm][j];
        s += v; s2 += v * v;
      }
    s += __shfl_xor(s, 16); s += __shfl_xor(s, 32);
    s2 += __shfl_xor(s2, 16); s2 += __shfl_xor(s2, 32);
    if (l < 16) { red[wid][fm * 16 + r16][0] = s; red[wid][fm * 16 + r16][1] = s2; }
  }
  __syncthreads();
  if (tid < 64) {
    float S = 0.f, S2 = 0.f;
#pragma unroll
    for (int w = 0; w < 8; ++w) { S += red[w][tid][0]; S2 += red[w][tid][1]; }
    float mu = S / F_;
    stats[tid][0] = mu;
    stats[tid][1] = rsqrtf(S2 / F_ - mu * mu + 1e-5f);
  }
  __syncthreads();

  if (!LAST) {
#pragma unroll
    for (int fn = 0; fn < 3; ++fn) {
      const int nb = wid * 48 + fn * 16 + q * 4;
      float g0 = g[nb], g1 = g[nb + 1], g2 = g[nb + 2], g3 = g[nb + 3];
      float e0 = be[nb], e1 = be[nb + 1], e2 = be[nb + 2], e3 = be[nb + 3];
#pragma unroll
      for (int fm = 0; fm < 4; ++fm) {
        const int m = fm * 16 + r16;
        const float mu = stats[m][0], rs = stats[m][1];
        float a0 = (acc[fn][fm][0] - mu) * rs * g0 + e0;
        float a1 = (acc[fn][fm][1] - mu) * rs * g1 + e1;
        float a2 = (acc[fn][fm][2] - mu) * rs * g2 + e2;
        float a3 = (acc[fn][fm][3] - mu) * rs * g3 + e3;
        uint32_t p0 = (uint32_t)f2bf(a0) | ((uint32_t)f2bf(a1) << 16);
        uint32_t p1 = (uint32_t)f2bf(a2) | ((uint32_t)f2bf(a3) << 16);
        *(uint2*)(xout + ((size_t)(b * PT + 1 + t0 + m)) * C_ + nb) =
            make_uint2(p0, p1);
      }
    }
  } else {
    float p[4] = {0.f, 0.f, 0.f, 0.f};
#pragma unroll
    for (int fn = 0; fn < 3; ++fn) {
      const int nb = wid * 48 + fn * 16 + q * 4;
      float g0 = g[nb], g1 = g[nb + 1], g2 = g[nb + 2], g3 = g[nb + 3];
      float e0 = be[nb], e1 = be[nb + 1], e2 = be[nb + 2], e3 = be[nb + 3];
      float l0 = wl[nb], l1 = wl[nb + 1], l2 = wl[nb + 2], l3 = wl[nb + 3];
#pragma unroll
      for (int fm = 0; fm < 4; ++fm) {
        const int m = fm * 16 + r16;
        const float mu = stats[m][0], rs = stats[m][1];
        p[fm] += ((acc[fn][fm][0] - mu) * rs * g0 + e0) * l0 +
                 ((acc[fn][fm][1] - mu) * rs * g1 + e1) * l1 +
                 ((acc[fn][fm][2] - mu) * rs * g2 + e2) * l2 +
                 ((acc[fn][fm][3] - mu) * rs * g3 + e3) * l3;
      }
    }
    __syncthreads();  // red reuse
#pragma unroll
    for (int fm = 0; fm < 4; ++fm) {
      float s = p[fm];
      s += __shfl_xor(s, 16); s += __shfl_xor(s, 32);
      if (l < 16) red[wid][fm * 16 + r16][0] = s;
    }
    __syncthreads();
    if (tid < 64) {
      float S = 0.f;
#pragma unroll
      for (int w = 0; w < 8; ++w) S += red[w][tid][0];
      int t = t0 + tid;
      dpo[b * T_ + t] = (S + bl[0]) * mask[b * T_ + t];
    }
  }
}

// ---------------------------------------------------------------------------
__global__ __launch_bounds__(256) void expand_kernel(
    const float* __restrict__ enc,  // [B,T,C] f32
    const int* __restrict__ cs,     // [B,T]
    float* __restrict__ out,        // [B,M,C]
    float* __restrict__ dec) {      // [B,M] (as float)
  __shared__ int scs[T_];
  const int blk = blockIdx.x;  // B * (M/4) blocks
  const int b = blk / (M_ / 4);
  const int p0 = (blk - b * (M_ / 4)) * 4;
  for (int i = threadIdx.x; i < T_; i += 256) scs[i] = cs[b * T_ + i];
  __syncthreads();

  const int lane = threadIdx.x & 63;
  const int wid = threadIdx.x >> 6;
  const int pos = p0 + wid;
  const int total = scs[T_ - 1];
  const bool valid = pos < total;

  int idx = 0;
#pragma unroll
  for (int step = 512; step; step >>= 1)
    if (idx + step <= T_ && scs[idx + step - 1] <= pos) idx += step;
  int src = idx < T_ ? idx : T_ - 1;

  const float4* srow = (const float4*)(enc + ((size_t)b * T_ + src) * C_);
  float4* orow = (float4*)(out + ((size_t)b * M_ + pos) * C_);
  const float4 zero = make_float4(0.f, 0.f, 0.f, 0.f);
#pragma unroll
  for (int j = 0; j < 2; ++j) {
    int c4 = j * 64 + lane;
    if (c4 < C_ / 4) orow[c4] = valid ? srow[c4] : zero;
  }
  if (lane == 0) dec[b * M_ + pos] = valid ? (float)(pos + 1) : 0.f;
}

// ---------------------------------------------------------------------------
extern "C" void kernel_launch(void* const* d_in, const int* in_sizes, int n_in,
                              void* d_out, int out_size, void* d_ws,
                              size_t ws_size, hipStream_t stream) {
  const float* enc    = (const float*)d_in[0];
  const float* mask   = (const float*)d_in[1];
  const int*   target = (const int*)d_in[2];
  const float* w1    = (const float*)d_in[4];
  const float* b1    = (const float*)d_in[5];
  const float* g1    = (const float*)d_in[6];
  const float* beta1 = (const float*)d_in[7];
  const float* w2    = (const float*)d_in[8];
  const float* b2    = (const float*)d_in[9];
  const float* g2    = (const float*)d_in[10];
  const float* beta2 = (const float*)d_in[11];
  const float* wl    = (const float*)d_in[12];
  const float* bl    = (const float*)d_in[13];

  // Workspace (bf16): xm | x1p (both padded) | wt1 | wt2 | cs (i32)
  ushort_t* xm  = (ushort_t*)d_ws;                    // [B][PT][C]
  ushort_t* x1p = xm + (size_t)B_ * PT * C_;          // [B][PT][C]
  ushort_t* wt1 = x1p + (size_t)B_ * PT * C_;         // [F][KTOT]
  ushort_t* wt2 = wt1 + (size_t)F_ * KTOT;
  int*      cs  = (int*)(wt2 + (size_t)F_ * KTOT);    // [B][T]

  float* out0 = (float*)d_out;                        // [B,M,C]
  float* dec  = out0 + (size_t)B_ * M_ * C_;          // [B,M]
  float* dpo  = dec + (size_t)B_ * M_;                // [B,T]

  prep_kernel<<<NXB + NWB + 8, 256, 0, stream>>>(
      enc, mask, target, w1, w2, xm, x1p, wt1, wt2, cs);

  gemm_ln_kernel<false><<<B_ * (T_ / 64), 512, 0, stream>>>(
      xm, wt1, b1, g1, beta1, nullptr, nullptr, nullptr, x1p, nullptr);
  gemm_ln_kernel<true><<<B_ * (T_ / 64), 512, 0, stream>>>(
      x1p, wt2, b2, g2, beta2, wl, bl, mask, nullptr, dpo);

  expand_kernel<<<(B_ * M_) / 4, 256, 0, stream>>>(enc, cs, out0, dec);
}